// Round 1
// baseline (2592.443 us; speedup 1.0000x reference)
//
#include <hip/hip_runtime.h>

#define D 2048
#define I_DIM 1408
#define E_NUM 16
#define NTOK 8192
#define BK 32

typedef _Float16 half8 __attribute__((ext_vector_type(8)));
typedef float float4v __attribute__((ext_vector_type(4)));

// ---------------- workspace layout (bytes) ----------------
// counts : int[16]              @ 0        (zeroed each launch)
// ids    : int[16*8192]         @ 1024     (packed tok*2 + k)
// wts    : float[16*8192]       @ 525312
// xb     : _Float16[8192*2048]  @ 1049600
// h      : _Float16[16384*1408] @ 34604032
// total ~81 MB

// ---------------- router ----------------
__global__ __launch_bounds__(256) void router_kernel(
    const float* __restrict__ x, const float* __restrict__ gw,
    _Float16* __restrict__ xb, int* __restrict__ counts,
    int* __restrict__ ids, float* __restrict__ wts)
{
    int t = blockIdx.x * 4 + (threadIdx.x >> 6);
    int lane = threadIdx.x & 63;
    const float* xr = x + (size_t)t * D;

    float acc[E_NUM];
#pragma unroll
    for (int e = 0; e < E_NUM; ++e) acc[e] = 0.f;

#pragma unroll 4
    for (int i = 0; i < D / 64; ++i) {
        int d = lane + i * 64;
        float xv = xr[d];
        xb[(size_t)t * D + d] = (_Float16)xv;
#pragma unroll
        for (int e = 0; e < E_NUM; ++e)
            acc[e] = fmaf(xv, gw[e * D + d], acc[e]);
    }
#pragma unroll
    for (int e = 0; e < E_NUM; ++e) {
        float v = acc[e];
#pragma unroll
        for (int m = 32; m >= 1; m >>= 1) v += __shfl_xor(v, m, 64);
        acc[e] = v;
    }
    if (lane == 0) {
        int e1 = 0; float l1 = acc[0];
#pragma unroll
        for (int e = 1; e < E_NUM; ++e)
            if (acc[e] > l1) { l1 = acc[e]; e1 = e; }
        int e2 = -1; float l2 = -3.0e38f;
#pragma unroll
        for (int e = 0; e < E_NUM; ++e) {
            if (e == e1) continue;
            if (acc[e] > l2) { l2 = acc[e]; e2 = e; }
        }
        // softmax top-2 renormalized: w1 = p1/(p1+p2) = 1/(1+exp(l2-l1))
        float w1 = 1.f / (1.f + expf(l2 - l1));
        float w2 = 1.f - w1;
        int s1 = atomicAdd(&counts[e1], 1);
        ids[e1 * NTOK + s1] = t * 2;     wts[e1 * NTOK + s1] = w1;
        int s2 = atomicAdd(&counts[e2], 1);
        ids[e2 * NTOK + s2] = t * 2 + 1; wts[e2 * NTOK + s2] = w2;
    }
}

// ---------------- stage 2: h = silu(x@wg) * (x@wu), gathered per expert ----------------
__global__ __launch_bounds__(256, 2) void moe_gateup_kernel(
    const _Float16* __restrict__ xb,
    const float* __restrict__ wg, const float* __restrict__ wu,
    const int* __restrict__ counts, const int* __restrict__ ids,
    _Float16* __restrict__ h)
{
    int e = blockIdx.z;
    int cnt = counts[e];
    int m0 = blockIdx.x * 128;
    if (m0 >= cnt) return;
    int n0 = blockIdx.y * 128;

    __shared__ __align__(16) _Float16 Als[128 * BK];
    __shared__ __align__(16) _Float16 Bg[BK * 128];
    __shared__ __align__(16) _Float16 Bu[BK * 128];
    __shared__ int rid[128];

    int tid = threadIdx.x;
    if (tid < 128) {
        int slot = m0 + tid;
        rid[tid] = (slot < cnt) ? ids[e * NTOK + slot] : -1;
    }
    __syncthreads();

    const float* wgE = wg + (size_t)e * D * I_DIM;
    const float* wuE = wu + (size_t)e * D * I_DIM;

    int wave = tid >> 6, lane = tid & 63;
    int wm = (wave & 1) * 64, wn = (wave >> 1) * 64;
    int lc = lane & 15, lq = lane >> 4;

    float4v accG[4][4], accU[4][4];
#pragma unroll
    for (int a = 0; a < 4; ++a)
#pragma unroll
        for (int b = 0; b < 4; ++b) {
            accG[a][b] = (float4v){0.f, 0.f, 0.f, 0.f};
            accU[a][b] = (float4v){0.f, 0.f, 0.f, 0.f};
        }

    int nn = tid & 127;
    int kb2 = tid >> 7;

    for (int k0 = 0; k0 < D; k0 += BK) {
        // ---- A staging: 128 rows x 32 halfs, gathered by token id ----
#pragma unroll
        for (int cc = 0; cc < 2; ++cc) {
            int c = tid + cc * 256;
            int row = c >> 2, kc = c & 3;
            int id = rid[row];
            uint4 v = {0u, 0u, 0u, 0u};
            if (id >= 0)
                v = *(const uint4*)(xb + (size_t)(id >> 1) * D + k0 + kc * 8);
            *(uint4*)(&Als[row * BK + kc * 8]) = v;
        }
        // ---- B staging: [32k x 128n] fp32 -> fp16, k-contiguous frag layout ----
#pragma unroll
        for (int kk = 0; kk < 2; ++kk) {
            int kb = kb2 * 2 + kk;
            const float* pg = wgE + (size_t)(k0 + kb * 8) * I_DIM + n0 + nn;
            const float* pu = wuE + (size_t)(k0 + kb * 8) * I_DIM + n0 + nn;
            half8 hg, hu;
#pragma unroll
            for (int j = 0; j < 8; ++j) {
                hg[j] = (_Float16)pg[(size_t)j * I_DIM];
                hu[j] = (_Float16)pu[(size_t)j * I_DIM];
            }
            *(half8*)(&Bg[(kb * 128 + nn) * 8]) = hg;
            *(half8*)(&Bu[(kb * 128 + nn) * 8]) = hu;
        }
        __syncthreads();

        half8 af[4];
#pragma unroll
        for (int ms = 0; ms < 4; ++ms)
            af[ms] = *(const half8*)(&Als[(wm + ms * 16 + lc) * BK + lq * 8]);
#pragma unroll
        for (int ns = 0; ns < 4; ++ns) {
            half8 bg = *(const half8*)(&Bg[(lq * 128 + wn + ns * 16 + lc) * 8]);
            half8 bu = *(const half8*)(&Bu[(lq * 128 + wn + ns * 16 + lc) * 8]);
#pragma unroll
            for (int ms = 0; ms < 4; ++ms) {
                accG[ms][ns] = __builtin_amdgcn_mfma_f32_16x16x32_f16(af[ms], bg, accG[ms][ns], 0, 0, 0);
                accU[ms][ns] = __builtin_amdgcn_mfma_f32_16x16x32_f16(af[ms], bu, accU[ms][ns], 0, 0, 0);
            }
        }
        __syncthreads();
    }

    // ---- epilogue: silu(g)*u -> h[id][n] fp16 ----
#pragma unroll
    for (int ms = 0; ms < 4; ++ms) {
#pragma unroll
        for (int r = 0; r < 4; ++r) {
            int row = wm + ms * 16 + lq * 4 + r;
            int id = rid[row];
            if (id >= 0) {
                _Float16* hr = h + (size_t)id * I_DIM + n0;
#pragma unroll
                for (int ns = 0; ns < 4; ++ns) {
                    float g = accG[ms][ns][r];
                    float u = accU[ms][ns][r];
                    float sv = g / (1.f + expf(-g)) * u;
                    hr[wn + ns * 16 + lc] = (_Float16)sv;
                }
            }
        }
    }
}

// ---------------- stage 3: out[tok] += w * (h_row @ wd[e]) ----------------
__global__ __launch_bounds__(256, 2) void moe_down_kernel(
    const _Float16* __restrict__ h, const float* __restrict__ wd,
    const int* __restrict__ counts, const int* __restrict__ ids,
    const float* __restrict__ wts, float* __restrict__ out)
{
    int e = blockIdx.z;
    int cnt = counts[e];
    int m0 = blockIdx.x * 128;
    if (m0 >= cnt) return;
    int n0 = blockIdx.y * 128;

    __shared__ __align__(16) _Float16 Als[128 * BK];
    __shared__ __align__(16) _Float16 Bd[BK * 128];
    __shared__ int rid[128];
    __shared__ float rw[128];

    int tid = threadIdx.x;
    if (tid < 128) {
        int slot = m0 + tid;
        int ok = slot < cnt;
        rid[tid] = ok ? ids[e * NTOK + slot] : -1;
        rw[tid]  = ok ? wts[e * NTOK + slot] : 0.f;
    }
    __syncthreads();

    const float* wdE = wd + (size_t)e * I_DIM * D;

    int wave = tid >> 6, lane = tid & 63;
    int wm = (wave & 1) * 64, wn = (wave >> 1) * 64;
    int lc = lane & 15, lq = lane >> 4;

    float4v acc[4][4];
#pragma unroll
    for (int a = 0; a < 4; ++a)
#pragma unroll
        for (int b = 0; b < 4; ++b)
            acc[a][b] = (float4v){0.f, 0.f, 0.f, 0.f};

    int nn = tid & 127;
    int kb2 = tid >> 7;

    for (int k0 = 0; k0 < I_DIM; k0 += BK) {
#pragma unroll
        for (int cc = 0; cc < 2; ++cc) {
            int c = tid + cc * 256;
            int row = c >> 2, kc = c & 3;
            int id = rid[row];
            uint4 v = {0u, 0u, 0u, 0u};
            if (id >= 0)
                v = *(const uint4*)(h + (size_t)id * I_DIM + k0 + kc * 8);
            *(uint4*)(&Als[row * BK + kc * 8]) = v;
        }
#pragma unroll
        for (int kk = 0; kk < 2; ++kk) {
            int kb = kb2 * 2 + kk;
            const float* pd = wdE + (size_t)(k0 + kb * 8) * D + n0 + nn;
            half8 hd;
#pragma unroll
            for (int j = 0; j < 8; ++j)
                hd[j] = (_Float16)pd[(size_t)j * D];
            *(half8*)(&Bd[(kb * 128 + nn) * 8]) = hd;
        }
        __syncthreads();

        half8 af[4];
#pragma unroll
        for (int ms = 0; ms < 4; ++ms)
            af[ms] = *(const half8*)(&Als[(wm + ms * 16 + lc) * BK + lq * 8]);
#pragma unroll
        for (int ns = 0; ns < 4; ++ns) {
            half8 bd = *(const half8*)(&Bd[(lq * 128 + wn + ns * 16 + lc) * 8]);
#pragma unroll
            for (int ms = 0; ms < 4; ++ms)
                acc[ms][ns] = __builtin_amdgcn_mfma_f32_16x16x32_f16(af[ms], bd, acc[ms][ns], 0, 0, 0);
        }
        __syncthreads();
    }

    // ---- epilogue: weighted atomic scatter-add into out ----
#pragma unroll
    for (int ms = 0; ms < 4; ++ms) {
#pragma unroll
        for (int r = 0; r < 4; ++r) {
            int row = wm + ms * 16 + lq * 4 + r;
            int id = rid[row];
            if (id >= 0) {
                int tok = id >> 1;
                float w = rw[row];
                float* orow = out + (size_t)tok * D + n0;
#pragma unroll
                for (int ns = 0; ns < 4; ++ns)
                    atomicAdd(&orow[wn + ns * 16 + lc], acc[ms][ns][r] * w);
            }
        }
    }
}

extern "C" void kernel_launch(void* const* d_in, const int* in_sizes, int n_in,
                              void* d_out, int out_size, void* d_ws, size_t ws_size,
                              hipStream_t stream) {
    const float* x  = (const float*)d_in[0];
    const float* gw = (const float*)d_in[1];
    const float* wg = (const float*)d_in[2];
    const float* wu = (const float*)d_in[3];
    const float* wd = (const float*)d_in[4];
    float* out = (float*)d_out;

    char* ws = (char*)d_ws;
    int*      counts = (int*)(ws);
    int*      ids    = (int*)(ws + 1024);
    float*    wts    = (float*)(ws + 525312);
    _Float16* xb     = (_Float16*)(ws + 1049600);
    _Float16* hbuf   = (_Float16*)(ws + 34604032);

    hipMemsetAsync(counts, 0, 1024, stream);
    hipMemsetAsync(d_out, 0, (size_t)out_size * sizeof(float), stream);

    router_kernel<<<dim3(NTOK / 4), dim3(256), 0, stream>>>(x, gw, xb, counts, ids, wts);
    moe_gateup_kernel<<<dim3(64, I_DIM / 128, E_NUM), dim3(256), 0, stream>>>(xb, wg, wu, counts, ids, hbuf);
    moe_down_kernel<<<dim3(64, D / 128, E_NUM), dim3(256), 0, stream>>>(hbuf, wd, counts, ids, wts, out);
}

// Round 2
// 1304.722 us; speedup vs baseline: 1.9870x; 1.9870x over previous
//
#include <hip/hip_runtime.h>

#define D 2048
#define I_DIM 1408
#define E_NUM 16
#define NTOK 8192
#define BK 32

typedef _Float16 half8 __attribute__((ext_vector_type(8)));
typedef float float4v __attribute__((ext_vector_type(4)));

// async global->LDS, 16B per lane; LDS dest = base + lane*16
#define GLL16(gp, lp)                                                        \
    __builtin_amdgcn_global_load_lds(                                        \
        (const __attribute__((address_space(1))) void*)(gp),                 \
        (__attribute__((address_space(3))) void*)(lp), 16, 0, 0)

// ---------------- fast-path workspace layout (bytes) ----------------
// counts @0 (1024) | ids @1024 (512K) | wts @525312 (512K) | wtk @1049600 (64K)
// xb @1115136 (32M) | h @34669568 (44M) | wgt @80806912 (88M) | wut @173081600 (88M)
// wdt aliases wgt (used after gateup) | part aliases wut (used after gateup)
// FAST_NEED = 265356288

// ---------------- router ----------------
__global__ __launch_bounds__(256) void router_kernel(
    const float* __restrict__ x, const float* __restrict__ gw,
    _Float16* __restrict__ xb, int* __restrict__ counts,
    int* __restrict__ ids, float* __restrict__ wts, float* __restrict__ wtk)
{
    int t = blockIdx.x * 4 + (threadIdx.x >> 6);
    int lane = threadIdx.x & 63;
    const float* xr = x + (size_t)t * D;

    float acc[E_NUM];
#pragma unroll
    for (int e = 0; e < E_NUM; ++e) acc[e] = 0.f;

#pragma unroll 4
    for (int i = 0; i < D / 64; ++i) {
        int d = lane + i * 64;
        float xv = xr[d];
        xb[(size_t)t * D + d] = (_Float16)xv;
#pragma unroll
        for (int e = 0; e < E_NUM; ++e)
            acc[e] = fmaf(xv, gw[e * D + d], acc[e]);
    }
#pragma unroll
    for (int e = 0; e < E_NUM; ++e) {
        float v = acc[e];
#pragma unroll
        for (int m = 32; m >= 1; m >>= 1) v += __shfl_xor(v, m, 64);
        acc[e] = v;
    }
    if (lane == 0) {
        int e1 = 0; float l1 = acc[0];
#pragma unroll
        for (int e = 1; e < E_NUM; ++e)
            if (acc[e] > l1) { l1 = acc[e]; e1 = e; }
        int e2 = -1; float l2 = -3.0e38f;
#pragma unroll
        for (int e = 0; e < E_NUM; ++e) {
            if (e == e1) continue;
            if (acc[e] > l2) { l2 = acc[e]; e2 = e; }
        }
        float w1 = 1.f / (1.f + expf(l2 - l1));
        float w2 = 1.f - w1;
        int s1 = atomicAdd(&counts[e1], 1);
        ids[e1 * NTOK + s1] = t * 2;     wts[e1 * NTOK + s1] = w1;
        int s2 = atomicAdd(&counts[e2], 1);
        ids[e2 * NTOK + s2] = t * 2 + 1; wts[e2 * NTOK + s2] = w2;
        wtk[t * 2] = w1; wtk[t * 2 + 1] = w2;
    }
}

// ---------------- transpose+convert: src fp32 [E][K][N] -> dst fp16 [E][N][K] ----------------
__global__ __launch_bounds__(256) void transpose_cvt_kernel(
    const float* __restrict__ src, _Float16* __restrict__ dst, int K, int N)
{
    int e = blockIdx.z;
    int k0 = blockIdx.x * 64;
    int n0 = blockIdx.y * 64;
    const float* s = src + (size_t)e * K * N;
    _Float16* d = dst + (size_t)e * N * K;

    __shared__ _Float16 T[64][68];
    int tid = threadIdx.x;
    int kl = tid >> 4;          // 0..15
    int n4 = (tid & 15) * 4;    // 0..60
#pragma unroll
    for (int p = 0; p < 4; ++p) {
        int k = p * 16 + kl;
        float4 v = *(const float4*)(s + (size_t)(k0 + k) * N + n0 + n4);
        T[n4 + 0][k] = (_Float16)v.x;
        T[n4 + 1][k] = (_Float16)v.y;
        T[n4 + 2][k] = (_Float16)v.z;
        T[n4 + 3][k] = (_Float16)v.w;
    }
    __syncthreads();
    int nl = tid >> 3;          // 0..31
    int kc = (tid & 7) * 8;     // 0..56
#pragma unroll
    for (int q = 0; q < 2; ++q) {
        int n = q * 32 + nl;
        half8 v;
#pragma unroll
        for (int j = 0; j < 8; ++j) v[j] = T[n][kc + j];
        *(half8*)(d + (size_t)(n0 + n) * K + k0 + kc) = v;
    }
}

// ---------------- fast gate+up: fp16 transposed weights, global_load_lds staging ----------------
__global__ __launch_bounds__(256, 2) void moe_gateup_f16(
    const _Float16* __restrict__ xb,
    const _Float16* __restrict__ wgt, const _Float16* __restrict__ wut,
    const int* __restrict__ counts, const int* __restrict__ ids,
    _Float16* __restrict__ h)
{
    int b = blockIdx.x;
    int g = b % 176;                 // n_tile (11, fast) x expert (16)
    int m0 = (b / 176) * 128;        // groups spaced 176 apart -> same XCD
    int e = g / 11;
    int n0 = (g % 11) * 128;
    int cnt = counts[e];
    if (m0 >= cnt) return;

    __shared__ __align__(16) _Float16 Als[128 * BK];
    __shared__ __align__(16) _Float16 Bg[128 * BK];
    __shared__ __align__(16) _Float16 Bu[128 * BK];
    __shared__ int rid[128];

    int tid = threadIdx.x;
    if (tid < 128) {
        int slot = m0 + tid;
        rid[tid] = (slot < cnt) ? ids[e * NTOK + slot] : -1;
    }
    __syncthreads();

    const _Float16* wgE = wgt + (size_t)e * I_DIM * D;
    const _Float16* wuE = wut + (size_t)e * I_DIM * D;

    int wave = tid >> 6, lane = tid & 63;
    int wm = (wave & 1) * 64, wn = (wave >> 1) * 64;
    int lc = lane & 15, lq = lane >> 4;
    int lrow = lane >> 2, lseg = (lane & 3) * 8;

    float4v accG[4][4], accU[4][4];
#pragma unroll
    for (int a = 0; a < 4; ++a)
#pragma unroll
        for (int c = 0; c < 4; ++c) {
            accG[a][c] = (float4v){0.f, 0.f, 0.f, 0.f};
            accU[a][c] = (float4v){0.f, 0.f, 0.f, 0.f};
        }

    for (int k0 = 0; k0 < D; k0 += BK) {
#pragma unroll
        for (int c = 0; c < 2; ++c) {
            int r0 = wave * 32 + c * 16;
            int row = r0 + lrow;
            int id = rid[row];
            int tr = (id >= 0) ? (id >> 1) : 0;
            GLL16(xb + (size_t)tr * D + k0 + lseg, &Als[r0 * BK]);
            GLL16(wgE + (size_t)(n0 + row) * D + k0 + lseg, &Bg[r0 * BK]);
            GLL16(wuE + (size_t)(n0 + row) * D + k0 + lseg, &Bu[r0 * BK]);
        }
        __syncthreads();

        half8 af[4];
#pragma unroll
        for (int ms = 0; ms < 4; ++ms)
            af[ms] = *(const half8*)(&Als[(wm + ms * 16 + lc) * BK + lq * 8]);
#pragma unroll
        for (int ns = 0; ns < 4; ++ns) {
            half8 bg = *(const half8*)(&Bg[(wn + ns * 16 + lc) * BK + lq * 8]);
            half8 bu = *(const half8*)(&Bu[(wn + ns * 16 + lc) * BK + lq * 8]);
#pragma unroll
            for (int ms = 0; ms < 4; ++ms) {
                accG[ms][ns] = __builtin_amdgcn_mfma_f32_16x16x32_f16(af[ms], bg, accG[ms][ns], 0, 0, 0);
                accU[ms][ns] = __builtin_amdgcn_mfma_f32_16x16x32_f16(af[ms], bu, accU[ms][ns], 0, 0, 0);
            }
        }
        __syncthreads();
    }

#pragma unroll
    for (int ms = 0; ms < 4; ++ms) {
#pragma unroll
        for (int r = 0; r < 4; ++r) {
            int row = wm + ms * 16 + lq * 4 + r;
            int id = rid[row];
            if (id >= 0) {
                _Float16* hr = h + (size_t)id * I_DIM + n0;
#pragma unroll
                for (int ns = 0; ns < 4; ++ns) {
                    float gv = accG[ms][ns][r];
                    float uv = accU[ms][ns][r];
                    float sv = gv / (1.f + expf(-gv)) * uv;
                    hr[wn + ns * 16 + lc] = (_Float16)sv;
                }
            }
        }
    }
}

// ---------------- fast down: fp16 transposed weights, writes fp16 partials ----------------
__global__ __launch_bounds__(256, 2) void moe_down_f16(
    const _Float16* __restrict__ h, const _Float16* __restrict__ wdt,
    const int* __restrict__ counts, const int* __restrict__ ids,
    _Float16* __restrict__ part)
{
    int b = blockIdx.x;
    int g = b % 256;                 // n_tile (16, fast) x expert (16)
    int m0 = (b / 256) * 128;        // spaced 256 apart -> same XCD
    int e = g >> 4;
    int n0 = (g & 15) * 128;
    int cnt = counts[e];
    if (m0 >= cnt) return;

    __shared__ __align__(16) _Float16 Als[128 * BK];
    __shared__ __align__(16) _Float16 Bd[128 * BK];
    __shared__ int rid[128];

    int tid = threadIdx.x;
    if (tid < 128) {
        int slot = m0 + tid;
        rid[tid] = (slot < cnt) ? ids[e * NTOK + slot] : -1;
    }
    __syncthreads();

    const _Float16* wdE = wdt + (size_t)e * D * I_DIM;

    int wave = tid >> 6, lane = tid & 63;
    int wm = (wave & 1) * 64, wn = (wave >> 1) * 64;
    int lc = lane & 15, lq = lane >> 4;
    int lrow = lane >> 2, lseg = (lane & 3) * 8;

    float4v acc[4][4];
#pragma unroll
    for (int a = 0; a < 4; ++a)
#pragma unroll
        for (int c = 0; c < 4; ++c)
            acc[a][c] = (float4v){0.f, 0.f, 0.f, 0.f};

    for (int k0 = 0; k0 < I_DIM; k0 += BK) {
#pragma unroll
        for (int c = 0; c < 2; ++c) {
            int r0 = wave * 32 + c * 16;
            int row = r0 + lrow;
            int id = rid[row];
            int tr = (id >= 0) ? id : 0;
            GLL16(h + (size_t)tr * I_DIM + k0 + lseg, &Als[r0 * BK]);
            GLL16(wdE + (size_t)(n0 + row) * I_DIM + k0 + lseg, &Bd[r0 * BK]);
        }
        __syncthreads();

        half8 af[4];
#pragma unroll
        for (int ms = 0; ms < 4; ++ms)
            af[ms] = *(const half8*)(&Als[(wm + ms * 16 + lc) * BK + lq * 8]);
#pragma unroll
        for (int ns = 0; ns < 4; ++ns) {
            half8 bd = *(const half8*)(&Bd[(wn + ns * 16 + lc) * BK + lq * 8]);
#pragma unroll
            for (int ms = 0; ms < 4; ++ms)
                acc[ms][ns] = __builtin_amdgcn_mfma_f32_16x16x32_f16(af[ms], bd, acc[ms][ns], 0, 0, 0);
        }
        __syncthreads();
    }

#pragma unroll
    for (int ms = 0; ms < 4; ++ms) {
#pragma unroll
        for (int r = 0; r < 4; ++r) {
            int row = wm + ms * 16 + lq * 4 + r;
            int id = rid[row];
            if (id >= 0) {
                _Float16* pr = part + (size_t)id * D + n0;
#pragma unroll
                for (int ns = 0; ns < 4; ++ns)
                    pr[wn + ns * 16 + lc] = (_Float16)acc[ms][ns][r];
            }
        }
    }
}

// ---------------- combine: out[t] = w1*part[2t] + w2*part[2t+1] ----------------
__global__ __launch_bounds__(256) void combine_kernel(
    const _Float16* __restrict__ part, const float* __restrict__ wtk,
    float* __restrict__ out)
{
    int t = blockIdx.x;
    int tid = threadIdx.x;
    float w1 = wtk[2 * t], w2 = wtk[2 * t + 1];
    const _Float16* p1 = part + (size_t)(2 * t) * D;
    const _Float16* p2 = p1 + D;
    float* o = out + (size_t)t * D;
    int i = tid * 8;
    half8 a = *(const half8*)(p1 + i);
    half8 bvec = *(const half8*)(p2 + i);
#pragma unroll
    for (int j = 0; j < 8; ++j)
        o[i + j] = w1 * (float)a[j] + w2 * (float)bvec[j];
}

// ================= fallback (round-1) kernels, fp32 weights =================
__global__ __launch_bounds__(256, 2) void moe_gateup_old(
    const _Float16* __restrict__ xb,
    const float* __restrict__ wg, const float* __restrict__ wu,
    const int* __restrict__ counts, const int* __restrict__ ids,
    _Float16* __restrict__ h)
{
    int e = blockIdx.z;
    int cnt = counts[e];
    int m0 = blockIdx.x * 128;
    if (m0 >= cnt) return;
    int n0 = blockIdx.y * 128;

    __shared__ __align__(16) _Float16 Als[128 * BK];
    __shared__ __align__(16) _Float16 Bg[BK * 128];
    __shared__ __align__(16) _Float16 Bu[BK * 128];
    __shared__ int rid[128];

    int tid = threadIdx.x;
    if (tid < 128) {
        int slot = m0 + tid;
        rid[tid] = (slot < cnt) ? ids[e * NTOK + slot] : -1;
    }
    __syncthreads();

    const float* wgE = wg + (size_t)e * D * I_DIM;
    const float* wuE = wu + (size_t)e * D * I_DIM;

    int wave = tid >> 6, lane = tid & 63;
    int wm = (wave & 1) * 64, wn = (wave >> 1) * 64;
    int lc = lane & 15, lq = lane >> 4;

    float4v accG[4][4], accU[4][4];
#pragma unroll
    for (int a = 0; a < 4; ++a)
#pragma unroll
        for (int c = 0; c < 4; ++c) {
            accG[a][c] = (float4v){0.f, 0.f, 0.f, 0.f};
            accU[a][c] = (float4v){0.f, 0.f, 0.f, 0.f};
        }

    int nn = tid & 127;
    int kb2 = tid >> 7;

    for (int k0 = 0; k0 < D; k0 += BK) {
#pragma unroll
        for (int cc = 0; cc < 2; ++cc) {
            int c = tid + cc * 256;
            int row = c >> 2, kc = c & 3;
            int id = rid[row];
            uint4 v = {0u, 0u, 0u, 0u};
            if (id >= 0)
                v = *(const uint4*)(xb + (size_t)(id >> 1) * D + k0 + kc * 8);
            *(uint4*)(&Als[row * BK + kc * 8]) = v;
        }
#pragma unroll
        for (int kk = 0; kk < 2; ++kk) {
            int kb = kb2 * 2 + kk;
            const float* pg = wgE + (size_t)(k0 + kb * 8) * I_DIM + n0 + nn;
            const float* pu = wuE + (size_t)(k0 + kb * 8) * I_DIM + n0 + nn;
            half8 hg, hu;
#pragma unroll
            for (int j = 0; j < 8; ++j) {
                hg[j] = (_Float16)pg[(size_t)j * I_DIM];
                hu[j] = (_Float16)pu[(size_t)j * I_DIM];
            }
            *(half8*)(&Bg[(kb * 128 + nn) * 8]) = hg;
            *(half8*)(&Bu[(kb * 128 + nn) * 8]) = hu;
        }
        __syncthreads();

        half8 af[4];
#pragma unroll
        for (int ms = 0; ms < 4; ++ms)
            af[ms] = *(const half8*)(&Als[(wm + ms * 16 + lc) * BK + lq * 8]);
#pragma unroll
        for (int ns = 0; ns < 4; ++ns) {
            half8 bg = *(const half8*)(&Bg[(lq * 128 + wn + ns * 16 + lc) * 8]);
            half8 bu = *(const half8*)(&Bu[(lq * 128 + wn + ns * 16 + lc) * 8]);
#pragma unroll
            for (int ms = 0; ms < 4; ++ms) {
                accG[ms][ns] = __builtin_amdgcn_mfma_f32_16x16x32_f16(af[ms], bg, accG[ms][ns], 0, 0, 0);
                accU[ms][ns] = __builtin_amdgcn_mfma_f32_16x16x32_f16(af[ms], bu, accU[ms][ns], 0, 0, 0);
            }
        }
        __syncthreads();
    }

#pragma unroll
    for (int ms = 0; ms < 4; ++ms) {
#pragma unroll
        for (int r = 0; r < 4; ++r) {
            int row = wm + ms * 16 + lq * 4 + r;
            int id = rid[row];
            if (id >= 0) {
                _Float16* hr = h + (size_t)id * I_DIM + n0;
#pragma unroll
                for (int ns = 0; ns < 4; ++ns) {
                    float gv = accG[ms][ns][r];
                    float uv = accU[ms][ns][r];
                    float sv = gv / (1.f + expf(-gv)) * uv;
                    hr[wn + ns * 16 + lc] = (_Float16)sv;
                }
            }
        }
    }
}

__global__ __launch_bounds__(256, 2) void moe_down_old(
    const _Float16* __restrict__ h, const float* __restrict__ wd,
    const int* __restrict__ counts, const int* __restrict__ ids,
    const float* __restrict__ wts, float* __restrict__ out)
{
    int e = blockIdx.z;
    int cnt = counts[e];
    int m0 = blockIdx.x * 128;
    if (m0 >= cnt) return;
    int n0 = blockIdx.y * 128;

    __shared__ __align__(16) _Float16 Als[128 * BK];
    __shared__ __align__(16) _Float16 Bd[BK * 128];
    __shared__ int rid[128];
    __shared__ float rw[128];

    int tid = threadIdx.x;
    if (tid < 128) {
        int slot = m0 + tid;
        int ok = slot < cnt;
        rid[tid] = ok ? ids[e * NTOK + slot] : -1;
        rw[tid]  = ok ? wts[e * NTOK + slot] : 0.f;
    }
    __syncthreads();

    const float* wdE = wd + (size_t)e * I_DIM * D;

    int wave = tid >> 6, lane = tid & 63;
    int wm = (wave & 1) * 64, wn = (wave >> 1) * 64;
    int lc = lane & 15, lq = lane >> 4;

    float4v acc[4][4];
#pragma unroll
    for (int a = 0; a < 4; ++a)
#pragma unroll
        for (int c = 0; c < 4; ++c)
            acc[a][c] = (float4v){0.f, 0.f, 0.f, 0.f};

    int nn = tid & 127;
    int kb2 = tid >> 7;

    for (int k0 = 0; k0 < I_DIM; k0 += BK) {
#pragma unroll
        for (int cc = 0; cc < 2; ++cc) {
            int c = tid + cc * 256;
            int row = c >> 2, kc = c & 3;
            int id = rid[row];
            uint4 v = {0u, 0u, 0u, 0u};
            if (id >= 0)
                v = *(const uint4*)(h + (size_t)id * I_DIM + k0 + kc * 8);
            *(uint4*)(&Als[row * BK + kc * 8]) = v;
        }
#pragma unroll
        for (int kk = 0; kk < 2; ++kk) {
            int kb = kb2 * 2 + kk;
            const float* pd = wdE + (size_t)(k0 + kb * 8) * D + n0 + nn;
            half8 hd;
#pragma unroll
            for (int j = 0; j < 8; ++j)
                hd[j] = (_Float16)pd[(size_t)j * D];
            *(half8*)(&Bd[(kb * 128 + nn) * 8]) = hd;
        }
        __syncthreads();

        half8 af[4];
#pragma unroll
        for (int ms = 0; ms < 4; ++ms)
            af[ms] = *(const half8*)(&Als[(wm + ms * 16 + lc) * BK + lq * 8]);
#pragma unroll
        for (int ns = 0; ns < 4; ++ns) {
            half8 bd = *(const half8*)(&Bd[(lq * 128 + wn + ns * 16 + lc) * 8]);
#pragma unroll
            for (int ms = 0; ms < 4; ++ms)
                acc[ms][ns] = __builtin_amdgcn_mfma_f32_16x16x32_f16(af[ms], bd, acc[ms][ns], 0, 0, 0);
        }
        __syncthreads();
    }

#pragma unroll
    for (int ms = 0; ms < 4; ++ms) {
#pragma unroll
        for (int r = 0; r < 4; ++r) {
            int row = wm + ms * 16 + lq * 4 + r;
            int id = rid[row];
            if (id >= 0) {
                int tok = id >> 1;
                float w = rw[row];
                float* orow = out + (size_t)tok * D + n0;
#pragma unroll
                for (int ns = 0; ns < 4; ++ns)
                    atomicAdd(&orow[wn + ns * 16 + lc], acc[ms][ns][r] * w);
            }
        }
    }
}

extern "C" void kernel_launch(void* const* d_in, const int* in_sizes, int n_in,
                              void* d_out, int out_size, void* d_ws, size_t ws_size,
                              hipStream_t stream) {
    const float* x  = (const float*)d_in[0];
    const float* gw = (const float*)d_in[1];
    const float* wg = (const float*)d_in[2];
    const float* wu = (const float*)d_in[3];
    const float* wd = (const float*)d_in[4];
    float* out = (float*)d_out;

    char* ws = (char*)d_ws;
    const size_t FAST_NEED = 265356288ull;

    if (ws_size >= FAST_NEED) {
        int*      counts = (int*)(ws);
        int*      ids    = (int*)(ws + 1024);
        float*    wts    = (float*)(ws + 525312);
        float*    wtk    = (float*)(ws + 1049600);
        _Float16* xb     = (_Float16*)(ws + 1115136);
        _Float16* hbuf   = (_Float16*)(ws + 34669568);
        _Float16* wgt    = (_Float16*)(ws + 80806912);
        _Float16* wut    = (_Float16*)(ws + 173081600);
        _Float16* wdt    = wgt;                       // alias: used after gateup
        _Float16* part   = wut;                       // alias: used after gateup

        hipMemsetAsync(counts, 0, 1024, stream);
        router_kernel<<<dim3(NTOK / 4), dim3(256), 0, stream>>>(x, gw, xb, counts, ids, wts, wtk);
        transpose_cvt_kernel<<<dim3(D / 64, I_DIM / 64, E_NUM), dim3(256), 0, stream>>>(wg, wgt, D, I_DIM);
        transpose_cvt_kernel<<<dim3(D / 64, I_DIM / 64, E_NUM), dim3(256), 0, stream>>>(wu, wut, D, I_DIM);
        moe_gateup_f16<<<dim3(176 * 64), dim3(256), 0, stream>>>(xb, wgt, wut, counts, ids, hbuf);
        transpose_cvt_kernel<<<dim3(I_DIM / 64, D / 64, E_NUM), dim3(256), 0, stream>>>(wd, wdt, I_DIM, D);
        moe_down_f16<<<dim3(256 * 64), dim3(256), 0, stream>>>(hbuf, wdt, counts, ids, part);
        combine_kernel<<<dim3(NTOK), dim3(256), 0, stream>>>(part, wtk, out);
    } else {
        // fallback: round-1 path (fp32 weights on the fly)
        int*      counts = (int*)(ws);
        int*      ids    = (int*)(ws + 1024);
        float*    wts    = (float*)(ws + 525312);
        _Float16* xb     = (_Float16*)(ws + 1049600);
        _Float16* hbuf   = (_Float16*)(ws + 34604032);
        float*    wtk    = (float*)(ws + 80741376);

        hipMemsetAsync(counts, 0, 1024, stream);
        hipMemsetAsync(d_out, 0, (size_t)out_size * sizeof(float), stream);
        router_kernel<<<dim3(NTOK / 4), dim3(256), 0, stream>>>(x, gw, xb, counts, ids, wts, wtk);
        moe_gateup_old<<<dim3(64, I_DIM / 128, E_NUM), dim3(256), 0, stream>>>(xb, wg, wu, counts, ids, hbuf);
        moe_down_old<<<dim3(64, D / 128, E_NUM), dim3(256), 0, stream>>>(hbuf, wd, counts, ids, wts, out);
    }
}